// Round 3
// baseline (1590.346 us; speedup 1.0000x reference)
//
#include <hip/hip_runtime.h>

#define TT 8

__device__ __forceinline__ float lrelu(float x){ return fmaxf(x, 0.2f*x); }

// One Euler IVP step for N states (4 or 2). 8-wave K-split, weights in VGPRs
// (64 floats/thread), partial sums combined through padded LDS P. 6 barriers.
// latOut: optional [64][N] destination for the updated z (decoder snapshots).
template<int N>
__device__ __forceinline__ void ivp_step(
    int tid, int w, int j, float tk, float adt,
    const float (&wA1)[8][2], const float (&wA2)[16][2], const float (&wA3)[16],
    float c_a1, float c_wt, float c_a2, float c_a3,
    float (*zS)[4], float (*h1S)[4], float (*h2S)[4],
    float (*P)[129][4], float* latOut)
{
  // ---- L1: z(64) -> h1(128); this wave covers K-rows [8w, 8w+8)
  {
    float a0[N], a1v[N];
    #pragma unroll
    for(int e=0;e<N;++e){ a0[e]=0.f; a1v[e]=0.f; }
    #pragma unroll
    for(int i=0;i<8;++i){
      float zv[N];
      if constexpr(N==4){ float4 t=*(const float4*)&zS[8*w+i][0]; zv[0]=t.x; zv[1]=t.y; zv[2]=t.z; zv[3]=t.w; }
      else              { float2 t=*(const float2*)&zS[8*w+i][0]; zv[0]=t.x; zv[1]=t.y; }
      #pragma unroll
      for(int e=0;e<N;++e){ a0[e]=fmaf(zv[e],wA1[i][0],a0[e]); a1v[e]=fmaf(zv[e],wA1[i][1],a1v[e]); }
    }
    if constexpr(N==4){
      *(float4*)&P[w][j][0]    = make_float4(a0[0],a0[1],a0[2],a0[3]);
      *(float4*)&P[w][j+64][0] = make_float4(a1v[0],a1v[1],a1v[2],a1v[3]);
    } else {
      *(float2*)&P[w][j][0]    = make_float2(a0[0],a0[1]);
      *(float2*)&P[w][j+64][0] = make_float2(a1v[0],a1v[1]);
    }
  }
  __syncthreads();
  if(tid<128){
    float s[N];
    #pragma unroll
    for(int e=0;e<N;++e) s[e]=fmaf(tk,c_wt,c_a1);
    #pragma unroll
    for(int kg=0;kg<8;++kg){
      if constexpr(N==4){ float4 t=*(const float4*)&P[kg][tid][0]; s[0]+=t.x; s[1]+=t.y; s[2]+=t.z; s[3]+=t.w; }
      else              { float2 t=*(const float2*)&P[kg][tid][0]; s[0]+=t.x; s[1]+=t.y; }
    }
    if constexpr(N==4) *(float4*)&h1S[tid][0]=make_float4(tanhf(s[0]),tanhf(s[1]),tanhf(s[2]),tanhf(s[3]));
    else               *(float2*)&h1S[tid][0]=make_float2(tanhf(s[0]),tanhf(s[1]));
  }
  __syncthreads();

  // ---- L2: h1(128) -> h2(128); K-rows [16w, 16w+16)
  {
    float a0[N], a1v[N];
    #pragma unroll
    for(int e=0;e<N;++e){ a0[e]=0.f; a1v[e]=0.f; }
    #pragma unroll
    for(int i=0;i<16;++i){
      float hv[N];
      if constexpr(N==4){ float4 t=*(const float4*)&h1S[16*w+i][0]; hv[0]=t.x; hv[1]=t.y; hv[2]=t.z; hv[3]=t.w; }
      else              { float2 t=*(const float2*)&h1S[16*w+i][0]; hv[0]=t.x; hv[1]=t.y; }
      #pragma unroll
      for(int e=0;e<N;++e){ a0[e]=fmaf(hv[e],wA2[i][0],a0[e]); a1v[e]=fmaf(hv[e],wA2[i][1],a1v[e]); }
    }
    if constexpr(N==4){
      *(float4*)&P[w][j][0]    = make_float4(a0[0],a0[1],a0[2],a0[3]);
      *(float4*)&P[w][j+64][0] = make_float4(a1v[0],a1v[1],a1v[2],a1v[3]);
    } else {
      *(float2*)&P[w][j][0]    = make_float2(a0[0],a0[1]);
      *(float2*)&P[w][j+64][0] = make_float2(a1v[0],a1v[1]);
    }
  }
  __syncthreads();
  if(tid<128){
    float s[N];
    #pragma unroll
    for(int e=0;e<N;++e) s[e]=c_a2;
    #pragma unroll
    for(int kg=0;kg<8;++kg){
      if constexpr(N==4){ float4 t=*(const float4*)&P[kg][tid][0]; s[0]+=t.x; s[1]+=t.y; s[2]+=t.z; s[3]+=t.w; }
      else              { float2 t=*(const float2*)&P[kg][tid][0]; s[0]+=t.x; s[1]+=t.y; }
    }
    if constexpr(N==4) *(float4*)&h2S[tid][0]=make_float4(tanhf(s[0]),tanhf(s[1]),tanhf(s[2]),tanhf(s[3]));
    else               *(float2*)&h2S[tid][0]=make_float2(tanhf(s[0]),tanhf(s[1]));
  }
  __syncthreads();

  // ---- L3: h2(128) -> dz(64); K-rows [16w, 16w+16)
  {
    float a0[N];
    #pragma unroll
    for(int e=0;e<N;++e) a0[e]=0.f;
    #pragma unroll
    for(int i=0;i<16;++i){
      float hv[N];
      if constexpr(N==4){ float4 t=*(const float4*)&h2S[16*w+i][0]; hv[0]=t.x; hv[1]=t.y; hv[2]=t.z; hv[3]=t.w; }
      else              { float2 t=*(const float2*)&h2S[16*w+i][0]; hv[0]=t.x; hv[1]=t.y; }
      #pragma unroll
      for(int e=0;e<N;++e) a0[e]=fmaf(hv[e],wA3[i],a0[e]);
    }
    if constexpr(N==4) *(float4*)&P[w][j][0]=make_float4(a0[0],a0[1],a0[2],a0[3]);
    else               *(float2*)&P[w][j][0]=make_float2(a0[0],a0[1]);
  }
  __syncthreads();
  if(tid<64){
    float d[N], zn[N];
    #pragma unroll
    for(int e=0;e<N;++e) d[e]=c_a3;
    #pragma unroll
    for(int kg=0;kg<8;++kg){
      if constexpr(N==4){ float4 t=*(const float4*)&P[kg][tid][0]; d[0]+=t.x; d[1]+=t.y; d[2]+=t.z; d[3]+=t.w; }
      else              { float2 t=*(const float2*)&P[kg][tid][0]; d[0]+=t.x; d[1]+=t.y; }
    }
    #pragma unroll
    for(int e=0;e<N;++e) zn[e]=fmaf(adt,d[e],zS[tid][e]);
    if constexpr(N==4) *(float4*)&zS[tid][0]=make_float4(zn[0],zn[1],zn[2],zn[3]);
    else               *(float2*)&zS[tid][0]=make_float2(zn[0],zn[1]);
    if(latOut){
      #pragma unroll
      for(int e=0;e<N;++e) latOut[tid*N+e]=zn[e];
    }
  }
  __syncthreads();
}

// ---------------- Encoder ----------------
// 1024 blocks x 512 thr. block = (sample pair) x (t-pair g: {7-g, g}).
// states: e0=(s0,ta) e1=(s1,ta) e2=(s0,tb) e3=(s1,tb). Phase1 (k<sb): 4 states;
// phase2 (sb<=k<sa): states {0,1}. Weights in VGPRs (64/thread), K-split 8 waves.
extern "C" __global__ void __launch_bounds__(512, 4)
k_enc(const float* __restrict__ features,
      const float* __restrict__ feW1, const float* __restrict__ feb1,
      const float* __restrict__ feW2, const float* __restrict__ feb2,
      const float* __restrict__ feW3, const float* __restrict__ feb3,
      const float* __restrict__ A1, const float* __restrict__ a1,
      const float* __restrict__ A2, const float* __restrict__ a2,
      const float* __restrict__ A3, const float* __restrict__ a3,
      const float* __restrict__ pW1, const float* __restrict__ pb1,
      const float* __restrict__ pW2, const float* __restrict__ pb2,
      float* __restrict__ ws_mu, float* __restrict__ ws_lv)
{
  __shared__ float zS[64][4];
  __shared__ float h1S[128][4];
  __shared__ float h2S[128][4];
  __shared__ float h2eS[64][4];
  __shared__ float P[8][129][4];
  const int tid=threadIdx.x, w=tid>>6, j=tid&63;
  const int g=blockIdx.x&3, chunk=blockIdx.x>>2, s0=chunk*2;
  const int ta=7-g, tb=g, sa=10*ta, sb=10*tb;

  // K-split weight registers: 16+32+16 = 64 floats/thread
  float wA1[8][2], wA2[16][2], wA3[16];
  #pragma unroll
  for(int i=0;i<8;++i){ wA1[i][0]=A1[(8*w+i)*128+j]; wA1[i][1]=A1[(8*w+i)*128+j+64]; }
  #pragma unroll
  for(int i=0;i<16;++i){ wA2[i][0]=A2[(16*w+i)*128+j]; wA2[i][1]=A2[(16*w+i)*128+j+64]; }
  #pragma unroll
  for(int i=0;i<16;++i){ wA3[i]=A3[(16*w+i)*64+j]; }

  float c_a1=0.f, c_wt=0.f, c_a2=0.f, c_a3=0.f;
  if(tid<128){ c_a1=a1[tid]; c_wt=A1[64*128+tid]; c_a2=a2[tid]; }
  if(tid<64){ c_a3=a3[tid]; }

  // ---- embedding: wave e<4 computes state e ----
  if(w<4){
    const int s=s0+(w&1);
    const int tv=(w<2)?ta:tb;
    const float* f=features+((size_t)s*TT+tv)*6;
    float x[6];
    #pragma unroll
    for(int i=0;i<6;++i) x[i]=f[i];
    float h0=feb1[j], h1v=feb1[j+64];
    #pragma unroll
    for(int i=0;i<6;++i){ h0=fmaf(x[i],feW1[i*128+j],h0); h1v=fmaf(x[i],feW1[i*128+j+64],h1v); }
    h1S[j][w]=lrelu(h0); h1S[j+64][w]=lrelu(h1v);
  }
  __syncthreads();
  if(w<4){
    float acc=feb2[j];
    #pragma unroll 8
    for(int i=0;i<128;++i) acc=fmaf(h1S[i][w], feW2[i*64+j], acc);
    h2eS[j][w]=lrelu(acc);
  }
  __syncthreads();
  if(w<4){
    float zz=feb3[j];
    #pragma unroll 8
    for(int i=0;i<64;++i) zz=fmaf(h2eS[i][w], feW3[i*64+j], zz);
    zS[j][w]=zz;
  }
  __syncthreads();

  // ---- IVP: lockstep (adt=-0.1, t_k=0.1k; both trajs start at local k=0) ----
  for(int k=0;k<sb;++k)
    ivp_step<4>(tid,w,j,0.1f*(float)k,-0.1f,wA1,wA2,wA3,c_a1,c_wt,c_a2,c_a3,zS,h1S,h2S,P,nullptr);
  for(int k=sb;k<sa;++k)
    ivp_step<2>(tid,w,j,0.1f*(float)k,-0.1f,wA1,wA2,wA3,c_a1,c_wt,c_a2,c_a3,zS,h1S,h2S,P,nullptr);

  // ---- posterior: wave e<4 handles state e (slots 2,3 preserved by phase2) ----
  if(w<4){
    float acc=pb1[j];
    #pragma unroll 8
    for(int i=0;i<64;++i) acc=fmaf(zS[i][w], pW1[i*64+j], acc);
    h2eS[j][w]=lrelu(acc);
  }
  __syncthreads();
  if(w<4){
    float m=pb2[j], l=pb2[j+64];
    #pragma unroll 8
    for(int i=0;i<64;++i){ float hv=h2eS[i][w]; m=fmaf(hv,pW2[i*128+j],m); l=fmaf(hv,pW2[i*128+j+64],l); }
    const int s=s0+(w&1);
    const int tv=(w<2)?ta:tb;
    size_t o=((size_t)s*TT+tv)*64+j;
    ws_mu[o]=m; ws_lv[o]=l;
  }
}

// ---------------- Decoder ----------------
// 256 blocks x 512 thr, 2 samples/block. mix+softmax+reparam; ONE shared
// 70-step trajectory (all _ivp(z0,t) prefixes), snapshot every 10 steps; rec MLP.
extern "C" __global__ void __launch_bounds__(512, 4)
k_dec(const float* __restrict__ mu_g, const float* __restrict__ lv_g,
      const float* __restrict__ eps,
      const float* __restrict__ mxW1, const float* __restrict__ mxb1,
      const float* __restrict__ mxW2, const float* __restrict__ mxb2,
      const float* __restrict__ A1, const float* __restrict__ a1,
      const float* __restrict__ A2, const float* __restrict__ a2,
      const float* __restrict__ A3, const float* __restrict__ a3,
      const float* __restrict__ rW1, const float* __restrict__ rb1,
      const float* __restrict__ rW2, const float* __restrict__ rb2,
      const float* __restrict__ rW3, const float* __restrict__ rb3,
      float* __restrict__ out)
{
  __shared__ float mu_s[2][8][64], lv_s[2][8][64];
  __shared__ float mh[2][8][32];
  __shared__ float wl[2][8];
  __shared__ float zS[64][4];
  __shared__ float h1S[128][4];
  __shared__ float h2S[128][4];
  __shared__ float P[8][129][4];
  __shared__ float LAT[8][64][2];
  __shared__ float h2r[64][2];
  const int tid=threadIdx.x, w=tid>>6, j=tid&63;
  const int b0=blockIdx.x*2;

  for(int idx=tid; idx<1024; idx+=512){
    ((float*)mu_s)[idx]=mu_g[(size_t)b0*512+idx];
    ((float*)lv_s)[idx]=lv_g[(size_t)b0*512+idx];
  }

  float wA1[8][2], wA2[16][2], wA3[16];
  #pragma unroll
  for(int i=0;i<8;++i){ wA1[i][0]=A1[(8*w+i)*128+j]; wA1[i][1]=A1[(8*w+i)*128+j+64]; }
  #pragma unroll
  for(int i=0;i<16;++i){ wA2[i][0]=A2[(16*w+i)*128+j]; wA2[i][1]=A2[(16*w+i)*128+j+64]; }
  #pragma unroll
  for(int i=0;i<16;++i){ wA3[i]=A3[(16*w+i)*64+j]; }
  float c_a1=0.f, c_wt=0.f, c_a2=0.f, c_a3=0.f;
  if(tid<128){ c_a1=a1[tid]; c_wt=A1[64*128+tid]; c_a2=a2[tid]; }
  if(tid<64){ c_a3=a3[tid]; }
  __syncthreads();

  // mixing hidden: thread -> (s,t,c)
  {
    int s=tid>>8, t=(tid>>5)&7, c=tid&31;
    float a=mxb1[c];
    #pragma unroll 8
    for(int i=0;i<64;++i) a=fmaf(mu_s[s][t][i], mxW1[i*32+c], a);
    mh[s][t][c]=lrelu(a);
  }
  __syncthreads();
  if(tid<16){
    int s=tid>>3, t=tid&7;
    float a=mxb2[0];
    #pragma unroll
    for(int i=0;i<32;++i) a=fmaf(mh[s][t][i], mxW2[i], a);
    wl[s][t]=a;
  }
  __syncthreads();
  if(tid<128){
    int s=tid>>6, jj=tid&63;
    float m=-1e30f;
    #pragma unroll
    for(int t=0;t<8;++t) m=fmaxf(m, wl[s][t]);
    float e[8], S=0.f;
    #pragma unroll
    for(int t=0;t<8;++t){ e[t]=expf(wl[s][t]-m); S+=e[t]; }
    float inv=1.f/S, mu0=0.f, lv0=0.f;
    #pragma unroll
    for(int t=0;t<8;++t){
      float wt=e[t]*inv;
      mu0=fmaf(wt, mu_s[s][t][jj], mu0);
      lv0=fmaf(wt, lv_s[s][t][jj], lv0);
    }
    float z0=fmaf(eps[(size_t)(b0+s)*64+jj], expf(0.5f*lv0), mu0);
    zS[jj][s]=z0; LAT[0][jj][s]=z0;
  }
  __syncthreads();

  // ---- shared 70-step forward trajectory, snapshot every 10 ----
  for(int k=0;k<70;++k){
    float* latp = (((k+1)%10)==0) ? &LAT[(k+1)/10][0][0] : nullptr;
    ivp_step<2>(tid,w,j,0.1f*(float)k,0.1f,wA1,wA2,wA3,c_a1,c_wt,c_a2,c_a3,zS,h1S,h2S,P,latp);
  }

  // ---- reconstruction MLP per t (weights from L2, coalesced) ----
  for(int t=0;t<8;++t){
    {
      int kg=tid>>7, col=tid&127;   // 4 kg x 16 rows
      float a0v=0.f, a1v=0.f;
      #pragma unroll
      for(int i=0;i<16;++i){
        float2 lv2=*(const float2*)&LAT[t][16*kg+i][0];
        float wv=rW1[(16*kg+i)*128+col];
        a0v=fmaf(lv2.x,wv,a0v); a1v=fmaf(lv2.y,wv,a1v);
      }
      *(float2*)&P[kg][col][0]=make_float2(a0v,a1v);
    }
    __syncthreads();
    if(tid<128){
      float s0v=rb1[tid], s1v=rb1[tid];
      #pragma unroll
      for(int kg=0;kg<4;++kg){ float2 t2=*(const float2*)&P[kg][tid][0]; s0v+=t2.x; s1v+=t2.y; }
      *(float2*)&h1S[tid][0]=make_float2(lrelu(s0v),lrelu(s1v));
    }
    __syncthreads();
    {
      int kg=tid>>6, col=tid&63;    // 8 kg x 16 rows
      float a0v=0.f, a1v=0.f;
      #pragma unroll
      for(int i=0;i<16;++i){
        float2 h2=*(const float2*)&h1S[16*kg+i][0];
        float wv=rW2[(16*kg+i)*64+col];
        a0v=fmaf(h2.x,wv,a0v); a1v=fmaf(h2.y,wv,a1v);
      }
      *(float2*)&P[kg][col][0]=make_float2(a0v,a1v);
    }
    __syncthreads();
    if(tid<64){
      float s0v=rb2[tid], s1v=rb2[tid];
      #pragma unroll
      for(int kg=0;kg<8;++kg){ float2 t2=*(const float2*)&P[kg][tid][0]; s0v+=t2.x; s1v+=t2.y; }
      h2r[tid][0]=lrelu(s0v); h2r[tid][1]=lrelu(s1v);
    }
    __syncthreads();
    if(tid<4){
      int s=tid>>1, o=tid&1;
      float a=rb3[o];
      #pragma unroll 8
      for(int i=0;i<64;++i) a=fmaf(h2r[i][s], rW3[i*2+o], a);
      out[((size_t)(b0+s)*TT+t)*2+o]=a;
    }
    __syncthreads();
  }
}

extern "C" void kernel_launch(void* const* d_in, const int* in_sizes, int n_in,
                              void* d_out, int out_size, void* d_ws, size_t ws_size,
                              hipStream_t stream){
  const float* features=(const float*)d_in[0];
  const float* eps     =(const float*)d_in[1];
  const float* feW1=(const float*)d_in[2];  const float* feb1=(const float*)d_in[3];
  const float* feW2=(const float*)d_in[4];  const float* feb2=(const float*)d_in[5];
  const float* feW3=(const float*)d_in[6];  const float* feb3=(const float*)d_in[7];
  const float* eA1=(const float*)d_in[8];   const float* ea1=(const float*)d_in[9];
  const float* eA2=(const float*)d_in[10];  const float* ea2=(const float*)d_in[11];
  const float* eA3=(const float*)d_in[12];  const float* ea3=(const float*)d_in[13];
  const float* pW1=(const float*)d_in[14];  const float* pb1=(const float*)d_in[15];
  const float* pW2=(const float*)d_in[16];  const float* pb2=(const float*)d_in[17];
  const float* mxW1=(const float*)d_in[18]; const float* mxb1=(const float*)d_in[19];
  const float* mxW2=(const float*)d_in[20]; const float* mxb2=(const float*)d_in[21];
  const float* dA1=(const float*)d_in[22];  const float* da1=(const float*)d_in[23];
  const float* dA2=(const float*)d_in[24];  const float* da2=(const float*)d_in[25];
  const float* dA3=(const float*)d_in[26];  const float* da3=(const float*)d_in[27];
  const float* rW1=(const float*)d_in[28];  const float* rb1=(const float*)d_in[29];
  const float* rW2=(const float*)d_in[30];  const float* rb2=(const float*)d_in[31];
  const float* rW3=(const float*)d_in[32];  const float* rb3=(const float*)d_in[33];

  float* ws_mu=(float*)d_ws;
  float* ws_lv=ws_mu + 512*8*64;

  k_enc<<<dim3(1024),dim3(512),0,stream>>>(features,
      feW1,feb1,feW2,feb2,feW3,feb3,
      eA1,ea1,eA2,ea2,eA3,ea3,
      pW1,pb1,pW2,pb2,
      ws_mu, ws_lv);
  k_dec<<<dim3(256),dim3(512),0,stream>>>(ws_mu, ws_lv, eps,
      mxW1,mxb1,mxW2,mxb2,
      dA1,da1,dA2,da2,dA3,da3,
      rW1,rb1,rW2,rb2,rW3,rb3,
      (float*)d_out);
}

// Round 4
// 1515.110 us; speedup vs baseline: 1.0497x; 1.0497x over previous
//
#include <hip/hip_runtime.h>

#define TT 8

__device__ __forceinline__ float lrelu(float x){ return fmaxf(x, 0.2f*x); }

// One Euler IVP step for NST states, 256-thread block, output-split (no
// cross-wave reductions). Acts in LDS [col][STR] (wave-uniform broadcast
// reads), weights streamed from global/L2 (lane-coalesced). 3 barriers.
// c1 = tid&127, sh = tid>>7 (uniform per wave); c3 = tid&63, sq = tid>>6.
template<int NST, int STR>
__device__ __forceinline__ void ivp_step(
    int c1, int sh, int c3, int sq, float tk, float adt,
    const float* __restrict__ A1, const float* __restrict__ a1,
    const float* __restrict__ A2, const float* __restrict__ a2,
    const float* __restrict__ A3, const float* __restrict__ a3,
    float (*zS)[STR], float (*h1S)[STR], float (*h2S)[STR], float* latRow)
{
  constexpr int S2 = (NST >= 2) ? NST/2 : 1;   // states/thread in L1,L2
  constexpr int S4 = (NST >= 4) ? NST/4 : 1;   // states/thread in L3

  // ---- L1: z(64) -> h1(128) ----
  {
    float wt = A1[64*128 + c1], b = a1[c1];
    float acc[S2];
    #pragma unroll
    for(int e=0;e<S2;++e) acc[e] = fmaf(tk, wt, b);
    #pragma unroll 4
    for(int i=0;i<64;++i){
      float w = A1[i*128 + c1];
      #pragma unroll
      for(int e=0;e<S2;++e) acc[e] = fmaf(zS[i][S2*sh+e], w, acc[e]);
    }
    #pragma unroll
    for(int e=0;e<S2;++e) h1S[c1][S2*sh+e] = tanhf(acc[e]);
  }
  __syncthreads();

  // ---- L2: h1(128) -> h2(128) ----
  {
    float b = a2[c1];
    float acc[S2];
    #pragma unroll
    for(int e=0;e<S2;++e) acc[e] = b;
    #pragma unroll 4
    for(int i=0;i<128;++i){
      float w = A2[i*128 + c1];
      #pragma unroll
      for(int e=0;e<S2;++e) acc[e] = fmaf(h1S[i][S2*sh+e], w, acc[e]);
    }
    #pragma unroll
    for(int e=0;e<S2;++e) h2S[c1][S2*sh+e] = tanhf(acc[e]);
  }
  __syncthreads();

  // ---- L3: h2(128) -> dz(64), Euler update ----
  {
    float b = a3[c3];
    float acc[S4];
    #pragma unroll
    for(int e=0;e<S4;++e) acc[e] = b;
    #pragma unroll 4
    for(int i=0;i<128;++i){
      float w = A3[i*64 + c3];
      #pragma unroll
      for(int e=0;e<S4;++e) acc[e] = fmaf(h2S[i][S4*sq+e], w, acc[e]);
    }
    #pragma unroll
    for(int e=0;e<S4;++e){
      float z = fmaf(adt, acc[e], zS[c3][S4*sq+e]);
      zS[c3][S4*sq+e] = z;
      if(latRow) latRow[c3*STR + S4*sq+e] = z;
    }
  }
  __syncthreads();
}

// ---------------- Encoder ----------------
// 256 blocks x 256 thr. block = (8-sample chunk) x (t-pair g: {7-g, g}).
// 16 states: e<8 -> (s0+e, ta), e>=8 -> (s0+e-8, tb). Phase1 (k<10*tb): 16
// states; phase2 (k<10*ta): states 0..7. Balanced: 560 state-steps per block.
extern "C" __global__ void __launch_bounds__(256)
k_enc(const float* __restrict__ features,
      const float* __restrict__ feW1, const float* __restrict__ feb1,
      const float* __restrict__ feW2, const float* __restrict__ feb2,
      const float* __restrict__ feW3, const float* __restrict__ feb3,
      const float* __restrict__ A1, const float* __restrict__ a1,
      const float* __restrict__ A2, const float* __restrict__ a2,
      const float* __restrict__ A3, const float* __restrict__ a3,
      const float* __restrict__ pW1, const float* __restrict__ pb1,
      const float* __restrict__ pW2, const float* __restrict__ pb2,
      float* __restrict__ ws_mu, float* __restrict__ ws_lv)
{
  __shared__ float zS[64][16];
  __shared__ float h1S[128][16];
  __shared__ float h2S[128][16];
  __shared__ float featS[16][8];
  const int tid=threadIdx.x;
  const int c1=tid&127, sh=tid>>7;   // sh uniform per wave
  const int c3=tid&63,  sq=tid>>6;   // sq uniform per wave
  const int g=blockIdx.x&3, chunk=blockIdx.x>>2, s0=chunk*8;
  const int ta=7-g, tb=g;

  // stage features for 16 states
  if(tid<96){
    int e=tid/6, i=tid-6*e;
    int s=s0+(e&7), tv=(e<8)?ta:tb;
    featS[e][i]=features[((size_t)s*TT+tv)*6+i];
  }
  __syncthreads();

  // ---- embedding L1: 6 -> 128 (8 states/thread) ----
  {
    float acc[8];
    float b=feb1[c1];
    #pragma unroll
    for(int e=0;e<8;++e) acc[e]=b;
    #pragma unroll
    for(int i=0;i<6;++i){
      float w=feW1[i*128+c1];
      #pragma unroll
      for(int e=0;e<8;++e) acc[e]=fmaf(featS[8*sh+e][i], w, acc[e]);
    }
    #pragma unroll
    for(int e=0;e<8;++e) h1S[c1][8*sh+e]=lrelu(acc[e]);
  }
  __syncthreads();
  // ---- embedding L2: 128 -> 64 (4 states/thread) ----
  {
    float acc[4];
    float b=feb2[c3];
    #pragma unroll
    for(int e=0;e<4;++e) acc[e]=b;
    #pragma unroll 4
    for(int i=0;i<128;++i){
      float w=feW2[i*64+c3];
      #pragma unroll
      for(int e=0;e<4;++e) acc[e]=fmaf(h1S[i][4*sq+e], w, acc[e]);
    }
    #pragma unroll
    for(int e=0;e<4;++e) h2S[c3][4*sq+e]=lrelu(acc[e]);
  }
  __syncthreads();
  // ---- embedding L3: 64 -> 64 ----
  {
    float acc[4];
    float b=feb3[c3];
    #pragma unroll
    for(int e=0;e<4;++e) acc[e]=b;
    #pragma unroll 4
    for(int i=0;i<64;++i){
      float w=feW3[i*64+c3];
      #pragma unroll
      for(int e=0;e<4;++e) acc[e]=fmaf(h2S[i][4*sq+e], w, acc[e]);
    }
    #pragma unroll
    for(int e=0;e<4;++e) zS[c3][4*sq+e]=acc[e];
  }
  __syncthreads();

  // ---- IVP: adt=-0.1, t_k=0.1k ----
  const int sb=10*tb, sa=10*ta;
  for(int k=0;k<sb;++k)
    ivp_step<16,16>(c1,sh,c3,sq,0.1f*(float)k,-0.1f,A1,a1,A2,a2,A3,a3,zS,h1S,h2S,nullptr);
  for(int k=sb;k<sa;++k)
    ivp_step<8,16>(c1,sh,c3,sq,0.1f*(float)k,-0.1f,A1,a1,A2,a2,A3,a3,zS,h1S,h2S,nullptr);

  // ---- posterior L1: 64 -> 64 ----
  {
    float acc[4];
    float b=pb1[c3];
    #pragma unroll
    for(int e=0;e<4;++e) acc[e]=b;
    #pragma unroll 4
    for(int i=0;i<64;++i){
      float w=pW1[i*64+c3];
      #pragma unroll
      for(int e=0;e<4;++e) acc[e]=fmaf(zS[i][4*sq+e], w, acc[e]);
    }
    #pragma unroll
    for(int e=0;e<4;++e) h2S[c3][4*sq+e]=lrelu(acc[e]);
  }
  __syncthreads();
  // ---- posterior L2: 64 -> 128 (cols 0..63 mu, 64..127 lv) ----
  {
    float acc[8];
    float b=pb2[c1];
    #pragma unroll
    for(int e=0;e<8;++e) acc[e]=b;
    #pragma unroll 4
    for(int i=0;i<64;++i){
      float w=pW2[i*128+c1];
      #pragma unroll
      for(int e=0;e<8;++e) acc[e]=fmaf(h2S[i][8*sh+e], w, acc[e]);
    }
    #pragma unroll
    for(int e=0;e<8;++e){
      int st=8*sh+e;
      int s=s0+(st&7), tv=(st<8)?ta:tb;
      size_t o=((size_t)s*TT+tv)*64;
      if(c1<64) ws_mu[o+c1]=acc[e];
      else      ws_lv[o+c1-64]=acc[e];
    }
  }
}

// ---------------- Decoder ----------------
// 128 blocks x 256 thr, 4 samples/block. mix+softmax+reparam; ONE shared
// 70-step trajectory (all _ivp(z0,t) are prefixes), snapshot every 10; rec MLP.
extern "C" __global__ void __launch_bounds__(256)
k_dec(const float* __restrict__ mu_g, const float* __restrict__ lv_g,
      const float* __restrict__ eps,
      const float* __restrict__ mxW1, const float* __restrict__ mxb1,
      const float* __restrict__ mxW2, const float* __restrict__ mxb2,
      const float* __restrict__ A1, const float* __restrict__ a1,
      const float* __restrict__ A2, const float* __restrict__ a2,
      const float* __restrict__ A3, const float* __restrict__ a3,
      const float* __restrict__ rW1, const float* __restrict__ rb1,
      const float* __restrict__ rW2, const float* __restrict__ rb2,
      const float* __restrict__ rW3, const float* __restrict__ rb3,
      float* __restrict__ out)
{
  __shared__ float mu_s[4][8][64], lv_s[4][8][64];
  __shared__ float mh[4][8][32];
  __shared__ float wsm[4][8];
  __shared__ float zS[64][4];
  __shared__ float h1S[128][4];
  __shared__ float h2S[128][4];
  __shared__ float LAT[TT][64][4];
  const int tid=threadIdx.x;
  const int c1=tid&127, sh=tid>>7;
  const int c3=tid&63,  sq=tid>>6;
  const int b0=blockIdx.x*4;

  for(int idx=tid; idx<2048; idx+=256){
    ((float*)mu_s)[idx]=mu_g[(size_t)b0*512+idx];
    ((float*)lv_s)[idx]=lv_g[(size_t)b0*512+idx];
  }
  __syncthreads();

  // mixing hidden: 4*8*32 outs
  for(int idx=tid; idx<1024; idx+=256){
    int s=idx>>8, t=(idx>>5)&7, c=idx&31;
    float a=mxb1[c];
    #pragma unroll 8
    for(int i=0;i<64;++i) a=fmaf(mu_s[s][t][i], mxW1[i*32+c], a);
    mh[s][t][c]=lrelu(a);
  }
  __syncthreads();
  if(tid<32){
    int s=tid>>3, t=tid&7;
    float a=mxb2[0];
    #pragma unroll
    for(int i=0;i<32;++i) a=fmaf(mh[s][t][i], mxW2[i], a);
    wsm[s][t]=a;
  }
  __syncthreads();
  if(tid<4){
    int s=tid;
    float m=-1e30f;
    #pragma unroll
    for(int t=0;t<8;++t) m=fmaxf(m, wsm[s][t]);
    float e[8], S=0.f;
    #pragma unroll
    for(int t=0;t<8;++t){ e[t]=expf(wsm[s][t]-m); S+=e[t]; }
    float inv=1.f/S;
    #pragma unroll
    for(int t=0;t<8;++t) wsm[s][t]=e[t]*inv;
  }
  __syncthreads();
  {
    int s=sq, c=c3;    // 4 waves x 64 cols
    float mu0=0.f, lv0=0.f;
    #pragma unroll
    for(int t=0;t<8;++t){
      float wv=wsm[s][t];
      mu0=fmaf(wv, mu_s[s][t][c], mu0);
      lv0=fmaf(wv, lv_s[s][t][c], lv0);
    }
    float z0=fmaf(eps[(size_t)(b0+s)*64+c], expf(0.5f*lv0), mu0);
    zS[c][s]=z0;
    LAT[0][c][s]=z0;
  }
  __syncthreads();

  // ---- shared 70-step forward trajectory (adt=+0.1), snapshot every 10 ----
  for(int k=0;k<70;++k){
    float* latRow = (((k+1)%10)==0) ? &LAT[(k+1)/10][0][0] : nullptr;
    ivp_step<4,4>(c1,sh,c3,sq,0.1f*(float)k,0.1f,A1,a1,A2,a2,A3,a3,zS,h1S,h2S,latRow);
  }

  // ---- reconstruction MLP per t ----
  for(int t=0;t<TT;++t){
    {
      float acc[2];
      float b=rb1[c1];
      acc[0]=b; acc[1]=b;
      #pragma unroll 4
      for(int i=0;i<64;++i){
        float w=rW1[i*128+c1];
        acc[0]=fmaf(LAT[t][i][2*sh  ], w, acc[0]);
        acc[1]=fmaf(LAT[t][i][2*sh+1], w, acc[1]);
      }
      h1S[c1][2*sh  ]=lrelu(acc[0]);
      h1S[c1][2*sh+1]=lrelu(acc[1]);
    }
    __syncthreads();
    {
      float a=rb2[c3];
      #pragma unroll 4
      for(int i=0;i<128;++i) a=fmaf(h1S[i][sq], rW2[i*64+c3], a);
      h2S[c3][sq]=lrelu(a);
    }
    __syncthreads();
    if(tid<8){
      int s=tid>>1, o=tid&1;
      float a=rb3[o];
      #pragma unroll 8
      for(int i=0;i<64;++i) a=fmaf(h2S[i][s], rW3[i*2+o], a);
      out[((size_t)(b0+s)*TT+t)*2+o]=a;
    }
    __syncthreads();
  }
}

extern "C" void kernel_launch(void* const* d_in, const int* in_sizes, int n_in,
                              void* d_out, int out_size, void* d_ws, size_t ws_size,
                              hipStream_t stream){
  const float* features=(const float*)d_in[0];
  const float* eps     =(const float*)d_in[1];
  const float* feW1=(const float*)d_in[2];  const float* feb1=(const float*)d_in[3];
  const float* feW2=(const float*)d_in[4];  const float* feb2=(const float*)d_in[5];
  const float* feW3=(const float*)d_in[6];  const float* feb3=(const float*)d_in[7];
  const float* eA1=(const float*)d_in[8];   const float* ea1=(const float*)d_in[9];
  const float* eA2=(const float*)d_in[10];  const float* ea2=(const float*)d_in[11];
  const float* eA3=(const float*)d_in[12];  const float* ea3=(const float*)d_in[13];
  const float* pW1=(const float*)d_in[14];  const float* pb1=(const float*)d_in[15];
  const float* pW2=(const float*)d_in[16];  const float* pb2=(const float*)d_in[17];
  const float* mxW1=(const float*)d_in[18]; const float* mxb1=(const float*)d_in[19];
  const float* mxW2=(const float*)d_in[20]; const float* mxb2=(const float*)d_in[21];
  const float* dA1=(const float*)d_in[22];  const float* da1=(const float*)d_in[23];
  const float* dA2=(const float*)d_in[24];  const float* da2=(const float*)d_in[25];
  const float* dA3=(const float*)d_in[26];  const float* da3=(const float*)d_in[27];
  const float* rW1=(const float*)d_in[28];  const float* rb1=(const float*)d_in[29];
  const float* rW2=(const float*)d_in[30];  const float* rb2=(const float*)d_in[31];
  const float* rW3=(const float*)d_in[32];  const float* rb3=(const float*)d_in[33];

  float* ws_mu=(float*)d_ws;
  float* ws_lv=ws_mu + 512*8*64;

  k_enc<<<dim3(256),dim3(256),0,stream>>>(features,
      feW1,feb1,feW2,feb2,feW3,feb3,
      eA1,ea1,eA2,ea2,eA3,ea3,
      pW1,pb1,pW2,pb2,
      ws_mu, ws_lv);
  k_dec<<<dim3(128),dim3(256),0,stream>>>(ws_mu, ws_lv, eps,
      mxW1,mxb1,mxW2,mxb2,
      dA1,da1,dA2,da2,dA3,da3,
      rW1,rb1,rW2,rb2,rW3,rb3,
      (float*)d_out);
}

// Round 5
// 482.852 us; speedup vs baseline: 3.2936x; 3.1378x over previous
//
#include <hip/hip_runtime.h>

#define TT 8

typedef __attribute__((ext_vector_type(4))) float f32x4;
typedef __attribute__((ext_vector_type(8))) short s16x8;
typedef __attribute__((ext_vector_type(4))) short s16x4;

__device__ __forceinline__ float lrelu(float x){ return fmaxf(x, 0.2f*x); }

// f32 -> bf16 (RNE) raw bits
__device__ __forceinline__ short f2b(float f){
  unsigned int u = __float_as_uint(f);
  unsigned int r = (u + 0x7fffu + ((u>>16)&1u)) >> 16;
  return (short)(r & 0xffffu);
}

// A-fragment for v_mfma_f32_16x16x32_bf16:
// lane l holds A[row = l&15][k = 8*(l>>4)+e], e=0..7.
// Here A(row=output col c, k=input i) = W[i][c], W row-major [K][ldw].
__device__ __forceinline__ s16x8 load_afrag(const float* __restrict__ W, int ldw,
                                            int k0, int c0, int lane){
  s16x8 f;
  const int r = lane & 15, kb = (lane >> 4) * 8;
  #pragma unroll
  for(int e=0;e<8;++e) f[e] = f2b(W[(size_t)(k0 + kb + e)*ldw + c0 + r]);
  return f;
}

// All IVP weights as register-resident MFMA fragments (per wave w of 4).
struct IvpFrags {
  s16x8 a1f[2][2];   // L1: 2 col-tiles x 2 k-tiles (K=64)
  s16x8 a2f[2][4];   // L2: 2 col-tiles x 4 k-tiles (K=128)
  s16x8 a3f[4];      // L3: 1 col-tile (wave's own) x 4 k-tiles
  float wt1[2][4], b1[2][4], b2[2][4], b3[4];
};

__device__ __forceinline__ void load_ivp_frags(IvpFrags& F,
    const float* __restrict__ A1, const float* __restrict__ a1,
    const float* __restrict__ A2, const float* __restrict__ a2,
    const float* __restrict__ A3, const float* __restrict__ a3,
    int w, int l){
  const int h = l >> 4;
  #pragma unroll
  for(int ct=0;ct<2;++ct){
    const int cg = 16*(2*w+ct);
    #pragma unroll
    for(int kt=0;kt<2;++kt) F.a1f[ct][kt] = load_afrag(A1, 128, 32*kt, cg, l);
    #pragma unroll
    for(int kt=0;kt<4;++kt) F.a2f[ct][kt] = load_afrag(A2, 128, 32*kt, cg, l);
    #pragma unroll
    for(int r=0;r<4;++r){
      const int c = cg + 4*h + r;
      F.wt1[ct][r] = A1[64*128 + c];   // time row of A1 (shape 65x128)
      F.b1[ct][r]  = a1[c];
      F.b2[ct][r]  = a2[c];
    }
  }
  #pragma unroll
  for(int kt=0;kt<4;++kt) F.a3f[kt] = load_afrag(A3, 64, 32*kt, 16*w, l);
  #pragma unroll
  for(int r=0;r<4;++r) F.b3[r] = a3[16*w + 4*h + r];
}

// One Euler step for 16 states via MFMA. B-operands are packed-bf16 LDS
// tiles: packedRow(k,st) = ((k>>3)<<4)|st, elem e = k&7; lane l of ktile kt
// reads row 64*kt + l as one b128 (linear 16B stride). z state lives in
// zreg[4] (lane owns rows c0=16w+4h+0..3, state st=l&15 == its L3 D-frag).
__device__ __forceinline__ void ivp_step_mfma(const IvpFrags& F, int w, int l,
    float tk, float adt, float (&zreg)[4],
    short* __restrict__ zB, short* __restrict__ h1p, short* __restrict__ h2p,
    float* __restrict__ latRow /* null or [64][16] f32 */){
  const int h = l >> 4, st = l & 15;
  // ---- L1: z(64) -> h1(128), + t-column, tanh ----
  #pragma unroll
  for(int ct=0;ct<2;++ct){
    f32x4 acc = {0.f,0.f,0.f,0.f};
    #pragma unroll
    for(int kt=0;kt<2;++kt){
      s16x8 b = *(const s16x8*)(zB + (size_t)(64*kt + l)*8);
      acc = __builtin_amdgcn_mfma_f32_16x16x32_bf16(F.a1f[ct][kt], b, acc, 0,0,0);
    }
    s16x4 pk;
    #pragma unroll
    for(int r=0;r<4;++r) pk[r] = f2b(tanhf(fmaf(tk, F.wt1[ct][r], acc[r]) + F.b1[ct][r]));
    const int row = (2*(2*w+ct) + (h>>1))*16 + st;
    *(s16x4*)(h1p + row*8 + 4*(h&1)) = pk;
  }
  __syncthreads();
  // ---- L2: h1(128) -> h2(128), tanh ----
  #pragma unroll
  for(int ct=0;ct<2;++ct){
    f32x4 acc = {0.f,0.f,0.f,0.f};
    #pragma unroll
    for(int kt=0;kt<4;++kt){
      s16x8 b = *(const s16x8*)(h1p + (size_t)(64*kt + l)*8);
      acc = __builtin_amdgcn_mfma_f32_16x16x32_bf16(F.a2f[ct][kt], b, acc, 0,0,0);
    }
    s16x4 pk;
    #pragma unroll
    for(int r=0;r<4;++r) pk[r] = f2b(tanhf(acc[r] + F.b2[ct][r]));
    const int row = (2*(2*w+ct) + (h>>1))*16 + st;
    *(s16x4*)(h2p + row*8 + 4*(h&1)) = pk;
  }
  __syncthreads();
  // ---- L3: h2(128) -> dz(64); Euler update in registers ----
  {
    f32x4 acc = {0.f,0.f,0.f,0.f};
    #pragma unroll
    for(int kt=0;kt<4;++kt){
      s16x8 b = *(const s16x8*)(h2p + (size_t)(64*kt + l)*8);
      acc = __builtin_amdgcn_mfma_f32_16x16x32_bf16(F.a3f[kt], b, acc, 0,0,0);
    }
    s16x4 pk;
    #pragma unroll
    for(int r=0;r<4;++r){
      zreg[r] = fmaf(adt, acc[r] + F.b3[r], zreg[r]);
      pk[r] = f2b(zreg[r]);
    }
    const int row = (2*w + (h>>1))*16 + st;
    *(s16x4*)(zB + row*8 + 4*(h&1)) = pk;
    if(latRow){
      const int c0 = 16*w + 4*h;
      #pragma unroll
      for(int r=0;r<4;++r) latRow[(c0+r)*16 + st] = zreg[r];
    }
  }
  __syncthreads();
}

// ---------------- Encoder ----------------
// 256 blocks x 256 thr. block = (16-sample chunk) x (single t). All 16
// states run exactly 10*t steps (uniform). Embedding/posterior in f32 VALU.
extern "C" __global__ void __launch_bounds__(256, 2)
k_enc(const float* __restrict__ features,
      const float* __restrict__ feW1, const float* __restrict__ feb1,
      const float* __restrict__ feW2, const float* __restrict__ feb2,
      const float* __restrict__ feW3, const float* __restrict__ feb3,
      const float* __restrict__ A1, const float* __restrict__ a1,
      const float* __restrict__ A2, const float* __restrict__ a2,
      const float* __restrict__ A3, const float* __restrict__ a3,
      const float* __restrict__ pW1, const float* __restrict__ pb1,
      const float* __restrict__ pW2, const float* __restrict__ pb2,
      float* __restrict__ ws_mu, float* __restrict__ ws_lv)
{
  __shared__ __align__(16) short zB[128*8];
  __shared__ __align__(16) short h1p[256*8];
  __shared__ __align__(16) short h2p[256*8];
  __shared__ float featS[16][6];
  __shared__ float hE1[128][16];
  __shared__ float hE2[64][16];
  __shared__ float zE[64][16];
  const int tid = threadIdx.x, l = tid & 63, w = tid >> 6;
  const int c1 = tid & 127, sh = tid >> 7;
  const int c3 = tid & 63,  sq = tid >> 6;
  const int t_blk = blockIdx.x & 7, chunk = blockIdx.x >> 3, s0 = chunk*16;

  IvpFrags F;
  load_ivp_frags(F, A1, a1, A2, a2, A3, a3, w, l);

  if(tid < 96){
    int e = tid / 6, i = tid - 6*e;
    featS[e][i] = features[((size_t)(s0+e)*TT + t_blk)*6 + i];
  }
  __syncthreads();
  // E1: 6 -> 128 (8 states/thread)
  {
    float acc[8]; const float b = feb1[c1];
    #pragma unroll
    for(int e=0;e<8;++e) acc[e]=b;
    #pragma unroll
    for(int i=0;i<6;++i){
      const float wv = feW1[i*128 + c1];
      #pragma unroll
      for(int e=0;e<8;++e) acc[e] = fmaf(featS[8*sh+e][i], wv, acc[e]);
    }
    #pragma unroll
    for(int e=0;e<8;++e) hE1[c1][8*sh+e] = lrelu(acc[e]);
  }
  __syncthreads();
  // E2: 128 -> 64 (4 states/thread)
  {
    float acc[4]; const float b = feb2[c3];
    #pragma unroll
    for(int e=0;e<4;++e) acc[e]=b;
    for(int i=0;i<128;++i){
      const float wv = feW2[i*64 + c3];
      #pragma unroll
      for(int e=0;e<4;++e) acc[e] = fmaf(hE1[i][4*sq+e], wv, acc[e]);
    }
    #pragma unroll
    for(int e=0;e<4;++e) hE2[c3][4*sq+e] = lrelu(acc[e]);
  }
  __syncthreads();
  // E3: 64 -> 64 (linear)
  {
    float acc[4]; const float b = feb3[c3];
    #pragma unroll
    for(int e=0;e<4;++e) acc[e]=b;
    for(int i=0;i<64;++i){
      const float wv = feW3[i*64 + c3];
      #pragma unroll
      for(int e=0;e<4;++e) acc[e] = fmaf(hE2[i][4*sq+e], wv, acc[e]);
    }
    #pragma unroll
    for(int e=0;e<4;++e) zE[c3][4*sq+e] = acc[e];
  }
  __syncthreads();
  // init z registers + packed zB
  float zreg[4];
  {
    const int h=l>>4, st=l&15, c0=16*w+4*h;
    s16x4 pk;
    #pragma unroll
    for(int r=0;r<4;++r){ zreg[r] = zE[c0+r][st]; pk[r]=f2b(zreg[r]); }
    const int row = (2*w + (h>>1))*16 + st;
    *(s16x4*)(zB + row*8 + 4*(h&1)) = pk;
  }
  __syncthreads();

  const int steps = 10*t_blk;
  for(int k=0;k<steps;++k)
    ivp_step_mfma(F, w, l, 0.1f*(float)k, -0.1f, zreg, zB, h1p, h2p, nullptr);

  // z back to f32 LDS for posterior
  {
    const int h=l>>4, st=l&15, c0=16*w+4*h;
    #pragma unroll
    for(int r=0;r<4;++r) zE[c0+r][st] = zreg[r];
  }
  __syncthreads();
  // posterior L1: 64 -> 64
  {
    float acc[4]; const float b = pb1[c3];
    #pragma unroll
    for(int e=0;e<4;++e) acc[e]=b;
    for(int i=0;i<64;++i){
      const float wv = pW1[i*64 + c3];
      #pragma unroll
      for(int e=0;e<4;++e) acc[e] = fmaf(zE[i][4*sq+e], wv, acc[e]);
    }
    #pragma unroll
    for(int e=0;e<4;++e) hE2[c3][4*sq+e] = lrelu(acc[e]);
  }
  __syncthreads();
  // posterior L2: 64 -> 128 (mu | lv)
  {
    float acc[8]; const float b = pb2[c1];
    #pragma unroll
    for(int e=0;e<8;++e) acc[e]=b;
    for(int i=0;i<64;++i){
      const float wv = pW2[i*128 + c1];
      #pragma unroll
      for(int e=0;e<8;++e) acc[e] = fmaf(hE2[i][8*sh+e], wv, acc[e]);
    }
    #pragma unroll
    for(int e=0;e<8;++e){
      const int s = s0 + 8*sh + e;
      const size_t o = ((size_t)s*TT + t_blk)*64;
      if(c1 < 64) ws_mu[o + c1] = acc[e];
      else        ws_lv[o + c1 - 64] = acc[e];
    }
  }
}

// ---------------- Decoder ----------------
// 32 blocks x 256 thr, 16 samples each. mix+softmax+reparam; ONE shared
// 70-step forward trajectory (all _ivp(z0,t) prefixes), snapshot every 10;
// reconstruction MLP in f32 VALU.
extern "C" __global__ void __launch_bounds__(256, 2)
k_dec(const float* __restrict__ mu_g, const float* __restrict__ lv_g,
      const float* __restrict__ eps,
      const float* __restrict__ mxW1, const float* __restrict__ mxb1,
      const float* __restrict__ mxW2, const float* __restrict__ mxb2,
      const float* __restrict__ A1, const float* __restrict__ a1,
      const float* __restrict__ A2, const float* __restrict__ a2,
      const float* __restrict__ A3, const float* __restrict__ a3,
      const float* __restrict__ rW1, const float* __restrict__ rb1,
      const float* __restrict__ rW2, const float* __restrict__ rb2,
      const float* __restrict__ rW3, const float* __restrict__ rb3,
      float* __restrict__ out)
{
  __shared__ __align__(16) short zB[128*8];
  __shared__ __align__(16) short h1p[256*8];
  __shared__ __align__(16) short h2p[256*8];
  __shared__ float muB[16*8*64];   // mu staging; reused as hR1/hR2 in rec phase
  __shared__ float lvB[16*8*64];
  __shared__ float LATS[TT][64][16];
  __shared__ float wsm[16][8];
  const int tid = threadIdx.x, l = tid & 63, w = tid >> 6;
  const int c1 = tid & 127, sh = tid >> 7;
  const int c3 = tid & 63,  sq = tid >> 6;
  const int b0 = blockIdx.x * 16;

  for(int idx=tid; idx<8192; idx+=256){
    muB[idx] = mu_g[(size_t)b0*512 + idx];
    lvB[idx] = lv_g[(size_t)b0*512 + idx];
  }
  IvpFrags F;
  load_ivp_frags(F, A1, a1, A2, a2, A3, a3, w, l);
  __syncthreads();

  // mixing logits wl[s][t] (one thread per (s,t))
  if(tid < 128){
    const int s = tid >> 3, t = tid & 7;
    const float* mrow = &muB[(s*8+t)*64];
    float acc2 = mxb2[0];
    for(int c=0;c<32;++c){
      float a = mxb1[c];
      for(int i=0;i<64;++i) a = fmaf(mrow[i], mxW1[i*32+c], a);
      acc2 = fmaf(lrelu(a), mxW2[c], acc2);
    }
    wsm[s][t] = acc2;
  }
  __syncthreads();
  if(tid < 16){
    float m = -1e30f;
    #pragma unroll
    for(int t=0;t<8;++t) m = fmaxf(m, wsm[tid][t]);
    float e[8], S=0.f;
    #pragma unroll
    for(int t=0;t<8;++t){ e[t] = expf(wsm[tid][t]-m); S += e[t]; }
    const float inv = 1.f/S;
    #pragma unroll
    for(int t=0;t<8;++t) wsm[tid][t] = e[t]*inv;
  }
  __syncthreads();
  // z0 (reparameterized), owner lanes
  float zreg[4];
  {
    const int h=l>>4, st=l&15, c0=16*w+4*h;
    s16x4 pk;
    #pragma unroll
    for(int r=0;r<4;++r){
      const int c = c0 + r;
      float mu0=0.f, lv0=0.f;
      #pragma unroll
      for(int t=0;t<8;++t){
        const float wv = wsm[st][t];
        mu0 = fmaf(wv, muB[(st*8+t)*64 + c], mu0);
        lv0 = fmaf(wv, lvB[(st*8+t)*64 + c], lv0);
      }
      const float z0 = fmaf(eps[(size_t)(b0+st)*64 + c], expf(0.5f*lv0), mu0);
      zreg[r] = z0; pk[r] = f2b(z0);
      LATS[0][c][st] = z0;
    }
    const int row = (2*w + (h>>1))*16 + st;
    *(s16x4*)(zB + row*8 + 4*(h&1)) = pk;
  }
  __syncthreads();

  for(int k=0;k<70;++k){
    float* latRow = (((k+1)%10)==0) ? &LATS[(k+1)/10][0][0] : nullptr;
    ivp_step_mfma(F, w, l, 0.1f*(float)k, 0.1f, zreg, zB, h1p, h2p, latRow);
  }

  // reconstruction MLP per t (f32; hR1/hR2 alias muB)
  float* hR1 = muB;            // [128][16]
  float* hR2 = muB + 128*16;   // [64][16]
  for(int t=0;t<TT;++t){
    {
      float acc[8]; const float b = rb1[c1];
      #pragma unroll
      for(int e=0;e<8;++e) acc[e]=b;
      for(int i=0;i<64;++i){
        const float wv = rW1[i*128 + c1];
        #pragma unroll
        for(int e=0;e<8;++e) acc[e] = fmaf(LATS[t][i][8*sh+e], wv, acc[e]);
      }
      #pragma unroll
      for(int e=0;e<8;++e) hR1[c1*16 + 8*sh + e] = lrelu(acc[e]);
    }
    __syncthreads();
    {
      float acc[4]; const float b = rb2[c3];
      #pragma unroll
      for(int e=0;e<4;++e) acc[e]=b;
      for(int i=0;i<128;++i){
        const float wv = rW2[i*64 + c3];
        #pragma unroll
        for(int e=0;e<4;++e) acc[e] = fmaf(hR1[i*16 + 4*sq + e], wv, acc[e]);
      }
      #pragma unroll
      for(int e=0;e<4;++e) hR2[c3*16 + 4*sq + e] = lrelu(acc[e]);
    }
    __syncthreads();
    if(tid < 32){
      const int s = tid >> 1, o = tid & 1;
      float a = rb3[o];
      for(int i=0;i<64;++i) a = fmaf(hR2[i*16 + s], rW3[i*2 + o], a);
      out[((size_t)(b0+s)*TT + t)*2 + o] = a;
    }
    __syncthreads();
  }
}

extern "C" void kernel_launch(void* const* d_in, const int* in_sizes, int n_in,
                              void* d_out, int out_size, void* d_ws, size_t ws_size,
                              hipStream_t stream){
  const float* features=(const float*)d_in[0];
  const float* eps     =(const float*)d_in[1];
  const float* feW1=(const float*)d_in[2];  const float* feb1=(const float*)d_in[3];
  const float* feW2=(const float*)d_in[4];  const float* feb2=(const float*)d_in[5];
  const float* feW3=(const float*)d_in[6];  const float* feb3=(const float*)d_in[7];
  const float* eA1=(const float*)d_in[8];   const float* ea1=(const float*)d_in[9];
  const float* eA2=(const float*)d_in[10];  const float* ea2=(const float*)d_in[11];
  const float* eA3=(const float*)d_in[12];  const float* ea3=(const float*)d_in[13];
  const float* pW1=(const float*)d_in[14];  const float* pb1=(const float*)d_in[15];
  const float* pW2=(const float*)d_in[16];  const float* pb2=(const float*)d_in[17];
  const float* mxW1=(const float*)d_in[18]; const float* mxb1=(const float*)d_in[19];
  const float* mxW2=(const float*)d_in[20]; const float* mxb2=(const float*)d_in[21];
  const float* dA1=(const float*)d_in[22];  const float* da1=(const float*)d_in[23];
  const float* dA2=(const float*)d_in[24];  const float* da2=(const float*)d_in[25];
  const float* dA3=(const float*)d_in[26];  const float* da3=(const float*)d_in[27];
  const float* rW1=(const float*)d_in[28];  const float* rb1=(const float*)d_in[29];
  const float* rW2=(const float*)d_in[30];  const float* rb2=(const float*)d_in[31];
  const float* rW3=(const float*)d_in[32];  const float* rb3=(const float*)d_in[33];

  float* ws_mu=(float*)d_ws;
  float* ws_lv=ws_mu + 512*8*64;

  k_enc<<<dim3(256),dim3(256),0,stream>>>(features,
      feW1,feb1,feW2,feb2,feW3,feb3,
      eA1,ea1,eA2,ea2,eA3,ea3,
      pW1,pb1,pW2,pb2,
      ws_mu, ws_lv);
  k_dec<<<dim3(32),dim3(256),0,stream>>>(ws_mu, ws_lv, eps,
      mxW1,mxb1,mxW2,mxb2,
      dA1,da1,dA2,da2,dA3,da3,
      rW1,rb1,rW2,rb2,rW3,rb3,
      (float*)d_out);
}

// Round 6
// 325.294 us; speedup vs baseline: 4.8889x; 1.4844x over previous
//
#include <hip/hip_runtime.h>

#define TT 8

typedef __attribute__((ext_vector_type(4))) float f32x4;
typedef __attribute__((ext_vector_type(8))) short s16x8;
typedef __attribute__((ext_vector_type(4))) short s16x4;

__device__ __forceinline__ float lrelu(float x){ return fmaxf(x, 0.2f*x); }

// branch-free tanh: exact at +-inf (exp->inf => 1; exp->0 => -1), ~1e-6 abs err
__device__ __forceinline__ float fast_tanh(float x){
  float e = __expf(2.f*x);
  return 1.f - 2.f/(e+1.f);
}

// f32 -> bf16 (RNE) raw bits
__device__ __forceinline__ short f2b(float f){
  unsigned int u = __float_as_uint(f);
  unsigned int r = (u + 0x7fffu + ((u>>16)&1u)) >> 16;
  return (short)(r & 0xffffu);
}

// A-fragment for v_mfma_f32_16x16x32_bf16:
// lane l holds A[row = l&15][k = 8*(l>>4)+e]. A(row=out col c, k=in i) = W[i][c].
__device__ __forceinline__ s16x8 load_afrag(const float* __restrict__ W, int ldw,
                                            int k0, int c0, int lane){
  s16x8 f;
  const int r = lane & 15, kb = (lane >> 4) * 8;
  #pragma unroll
  for(int e=0;e<8;++e) f[e] = f2b(W[(size_t)(k0 + kb + e)*ldw + c0 + r]);
  return f;
}

// Per-wave fragments: wave w owns out-cols [16w,16w+16) of L1/L2 (8 waves),
// and (if w<4) out-cols [16w,16w+16) of L3.
struct Frags {
  s16x8 a1f[2];            // L1: K=64 -> 2 k-tiles
  s16x8 a2f[4];            // L2: K=128 -> 4 k-tiles
  s16x8 a3f[4];            // L3 (w<4): K=128
  float wt1[4], b1[4], b2[4], b3[4];
};

__device__ __forceinline__ void load_frags(Frags& F,
    const float* __restrict__ A1, const float* __restrict__ a1,
    const float* __restrict__ A2, const float* __restrict__ a2,
    const float* __restrict__ A3, const float* __restrict__ a3,
    int w, int l){
  const int h = l >> 4;
  #pragma unroll
  for(int kt=0;kt<2;++kt) F.a1f[kt] = load_afrag(A1, 128, 32*kt, 16*w, l);
  #pragma unroll
  for(int kt=0;kt<4;++kt) F.a2f[kt] = load_afrag(A2, 128, 32*kt, 16*w, l);
  #pragma unroll
  for(int r=0;r<4;++r){
    const int c = 16*w + 4*h + r;
    F.wt1[r] = A1[64*128 + c];   // time row (A1 is 65x128)
    F.b1[r]  = a1[c];
    F.b2[r]  = a2[c];
  }
  if(w < 4){
    #pragma unroll
    for(int kt=0;kt<4;++kt) F.a3f[kt] = load_afrag(A3, 64, 32*kt, 16*w, l);
    #pragma unroll
    for(int r=0;r<4;++r) F.b3[r] = a3[16*w + 4*h + r];
  }
}

// One Euler step for 16 states. Packed-bf16 LDS B layout: row(k,st)=((k>>3)<<4)|st,
// elem k&7; lane l of k-tile kt reads row 64*kt+l as one b128. D k-row 16w+4h+r
// packs to row (2w+(h>>1))*16+st, elem 4(h&1)+r. z lives in zreg on waves 0-3.
__device__ __forceinline__ void ivp_step(const Frags& F, int w, int l,
    float tk, float adt, float (&zreg)[4],
    short* __restrict__ zB, short* __restrict__ h1p, short* __restrict__ h2p,
    float* __restrict__ latRow){
  const int h = l>>4, st = l&15;
  const int wrow = (2*w + (h>>1))*16 + st;
  const int welem = 4*(h&1);
  // ---- L1: z(64) -> h1(128) ----
  {
    s16x8 bz0 = *(const s16x8*)(zB + (size_t)l*8);
    s16x8 bz1 = *(const s16x8*)(zB + (size_t)(64+l)*8);
    f32x4 acc = {0.f,0.f,0.f,0.f};
    acc = __builtin_amdgcn_mfma_f32_16x16x32_bf16(F.a1f[0], bz0, acc, 0,0,0);
    acc = __builtin_amdgcn_mfma_f32_16x16x32_bf16(F.a1f[1], bz1, acc, 0,0,0);
    s16x4 pk;
    #pragma unroll
    for(int r=0;r<4;++r) pk[r] = f2b(fast_tanh(fmaf(tk, F.wt1[r], acc[r]) + F.b1[r]));
    *(s16x4*)(h1p + (size_t)wrow*8 + welem) = pk;
  }
  __syncthreads();
  // ---- L2: h1(128) -> h2(128) ----
  {
    f32x4 acc = {0.f,0.f,0.f,0.f};
    #pragma unroll
    for(int kt=0;kt<4;++kt){
      s16x8 b = *(const s16x8*)(h1p + (size_t)(64*kt + l)*8);
      acc = __builtin_amdgcn_mfma_f32_16x16x32_bf16(F.a2f[kt], b, acc, 0,0,0);
    }
    s16x4 pk;
    #pragma unroll
    for(int r=0;r<4;++r) pk[r] = f2b(fast_tanh(acc[r] + F.b2[r]));
    *(s16x4*)(h2p + (size_t)wrow*8 + welem) = pk;
  }
  __syncthreads();
  // ---- L3: h2(128) -> dz(64); Euler update on waves 0-3 ----
  if(w < 4){
    f32x4 acc = {0.f,0.f,0.f,0.f};
    #pragma unroll
    for(int kt=0;kt<4;++kt){
      s16x8 b = *(const s16x8*)(h2p + (size_t)(64*kt + l)*8);
      acc = __builtin_amdgcn_mfma_f32_16x16x32_bf16(F.a3f[kt], b, acc, 0,0,0);
    }
    s16x4 pk;
    #pragma unroll
    for(int r=0;r<4;++r){
      zreg[r] = fmaf(adt, acc[r] + F.b3[r], zreg[r]);
      pk[r] = f2b(zreg[r]);
    }
    *(s16x4*)(zB + (size_t)wrow*8 + welem) = pk;
    if(latRow){
      #pragma unroll
      for(int r=0;r<4;++r) latRow[(16*w + 4*h + r)*16 + st] = zreg[r];
    }
  }
  __syncthreads();
}

// ---------------- Encoder ----------------
// 256 blocks x 512 thr. block = (16-sample chunk) x (single t); 10*t uniform steps.
extern "C" __global__ void __launch_bounds__(512, 2)
k_enc(const float* __restrict__ features,
      const float* __restrict__ feW1, const float* __restrict__ feb1,
      const float* __restrict__ feW2, const float* __restrict__ feb2,
      const float* __restrict__ feW3, const float* __restrict__ feb3,
      const float* __restrict__ A1, const float* __restrict__ a1,
      const float* __restrict__ A2, const float* __restrict__ a2,
      const float* __restrict__ A3, const float* __restrict__ a3,
      const float* __restrict__ pW1, const float* __restrict__ pb1,
      const float* __restrict__ pW2, const float* __restrict__ pb2,
      float* __restrict__ ws_mu, float* __restrict__ ws_lv)
{
  __shared__ __align__(16) short zB[128*8];
  __shared__ __align__(16) short h1p[256*8];
  __shared__ __align__(16) short h2p[256*8];
  __shared__ float featS[16][6];
  __shared__ float hE1[128][16];
  __shared__ float hE2[64][16];
  __shared__ float zE[64][16];
  const int tid = threadIdx.x, l = tid & 63, w = tid >> 6;      // 8 waves
  const int c1 = tid & 127, sh = tid >> 7;                      // sh in [0,4)
  const int t_blk = blockIdx.x & 7, chunk = blockIdx.x >> 3, s0 = chunk*16;

  Frags F;
  load_frags(F, A1, a1, A2, a2, A3, a3, w, l);

  if(tid < 96){
    int e = tid / 6, i = tid - 6*e;
    featS[e][i] = features[((size_t)(s0+e)*TT + t_blk)*6 + i];
  }
  __syncthreads();
  // E1: 6 -> 128 (4 states/thread)
  {
    float acc[4]; const float b = feb1[c1];
    #pragma unroll
    for(int e=0;e<4;++e) acc[e]=b;
    #pragma unroll
    for(int i=0;i<6;++i){
      const float wv = feW1[i*128 + c1];
      #pragma unroll
      for(int e=0;e<4;++e) acc[e] = fmaf(featS[4*sh+e][i], wv, acc[e]);
    }
    #pragma unroll
    for(int e=0;e<4;++e) hE1[c1][4*sh+e] = lrelu(acc[e]);
  }
  __syncthreads();
  // E2: 128 -> 64 (2 states/thread)
  {
    float acc[2]; const float b = feb2[l];
    acc[0]=b; acc[1]=b;
    for(int i=0;i<128;++i){
      const float wv = feW2[i*64 + l];
      acc[0] = fmaf(hE1[i][2*w  ], wv, acc[0]);
      acc[1] = fmaf(hE1[i][2*w+1], wv, acc[1]);
    }
    hE2[l][2*w  ] = lrelu(acc[0]);
    hE2[l][2*w+1] = lrelu(acc[1]);
  }
  __syncthreads();
  // E3: 64 -> 64 (linear)
  {
    float acc[2]; const float b = feb3[l];
    acc[0]=b; acc[1]=b;
    for(int i=0;i<64;++i){
      const float wv = feW3[i*64 + l];
      acc[0] = fmaf(hE2[i][2*w  ], wv, acc[0]);
      acc[1] = fmaf(hE2[i][2*w+1], wv, acc[1]);
    }
    zE[l][2*w  ] = acc[0];
    zE[l][2*w+1] = acc[1];
  }
  __syncthreads();
  // init z registers + packed zB (waves 0-3)
  float zreg[4] = {0.f,0.f,0.f,0.f};
  if(w < 4){
    const int h=l>>4, st=l&15;
    s16x4 pk;
    #pragma unroll
    for(int r=0;r<4;++r){ zreg[r] = zE[16*w+4*h+r][st]; pk[r]=f2b(zreg[r]); }
    *(s16x4*)(zB + (size_t)((2*w+(h>>1))*16+st)*8 + 4*(h&1)) = pk;
  }
  __syncthreads();

  const int steps = 10*t_blk;
  for(int k=0;k<steps;++k)
    ivp_step(F, w, l, 0.1f*(float)k, -0.1f, zreg, zB, h1p, h2p, nullptr);

  // z back to f32 LDS
  if(w < 4){
    const int h=l>>4, st=l&15;
    #pragma unroll
    for(int r=0;r<4;++r) zE[16*w+4*h+r][st] = zreg[r];
  }
  __syncthreads();
  // posterior L1: 64 -> 64 (2 states/thread)
  {
    float acc[2]; const float b = pb1[l];
    acc[0]=b; acc[1]=b;
    for(int i=0;i<64;++i){
      const float wv = pW1[i*64 + l];
      acc[0] = fmaf(zE[i][2*w  ], wv, acc[0]);
      acc[1] = fmaf(zE[i][2*w+1], wv, acc[1]);
    }
    hE2[l][2*w  ] = lrelu(acc[0]);
    hE2[l][2*w+1] = lrelu(acc[1]);
  }
  __syncthreads();
  // posterior L2: 64 -> 128 (mu | lv), 4 states/thread
  {
    float acc[4]; const float b = pb2[c1];
    #pragma unroll
    for(int e=0;e<4;++e) acc[e]=b;
    for(int i=0;i<64;++i){
      const float wv = pW2[i*128 + c1];
      #pragma unroll
      for(int e=0;e<4;++e) acc[e] = fmaf(hE2[i][4*sh+e], wv, acc[e]);
    }
    #pragma unroll
    for(int e=0;e<4;++e){
      const int s = s0 + 4*sh + e;
      const size_t o = ((size_t)s*TT + t_blk)*64;
      if(c1 < 64) ws_mu[o + c1] = acc[e];
      else        ws_lv[o + c1 - 64] = acc[e];
    }
  }
}

// ---------------- Decoder ----------------
// 32 blocks x 512 thr, 16 samples each; ONE shared 70-step trajectory
// (all _ivp(z0,t) are prefixes), snapshot every 10 steps; rec MLP.
extern "C" __global__ void __launch_bounds__(512, 2)
k_dec(const float* __restrict__ mu_g, const float* __restrict__ lv_g,
      const float* __restrict__ eps,
      const float* __restrict__ mxW1, const float* __restrict__ mxb1,
      const float* __restrict__ mxW2, const float* __restrict__ mxb2,
      const float* __restrict__ A1, const float* __restrict__ a1,
      const float* __restrict__ A2, const float* __restrict__ a2,
      const float* __restrict__ A3, const float* __restrict__ a3,
      const float* __restrict__ rW1, const float* __restrict__ rb1,
      const float* __restrict__ rW2, const float* __restrict__ rb2,
      const float* __restrict__ rW3, const float* __restrict__ rb3,
      float* __restrict__ out)
{
  __shared__ __align__(16) short zB[128*8];
  __shared__ __align__(16) short h1p[256*8];
  __shared__ __align__(16) short h2p[256*8];
  __shared__ float muB[16*8*64];   // reused as hR1/hR2 in rec phase
  __shared__ float lvB[16*8*64];
  __shared__ float mh[16][8][32];
  __shared__ float LATS[TT][64][16];
  __shared__ float wsm[16][8];
  const int tid = threadIdx.x, l = tid & 63, w = tid >> 6;
  const int c1 = tid & 127, sh = tid >> 7;
  const int b0 = blockIdx.x * 16;

  for(int idx=tid; idx<8192; idx+=512){
    muB[idx] = mu_g[(size_t)b0*512 + idx];
    lvB[idx] = lv_g[(size_t)b0*512 + idx];
  }
  Frags F;
  load_frags(F, A1, a1, A2, a2, A3, a3, w, l);
  __syncthreads();

  // mixing hidden (parallel: 4096 items / 512 thr)
  for(int idx=tid; idx<4096; idx+=512){
    const int s = idx>>8, t = (idx>>5)&7, c = idx&31;
    float a = mxb1[c];
    #pragma unroll 8
    for(int i=0;i<64;++i) a = fmaf(muB[(s*8+t)*64+i], mxW1[i*32+c], a);
    mh[s][t][c] = lrelu(a);
  }
  __syncthreads();
  if(tid < 128){
    const int s = tid>>3, t = tid&7;
    float a = mxb2[0];
    #pragma unroll
    for(int i=0;i<32;++i) a = fmaf(mh[s][t][i], mxW2[i], a);
    wsm[s][t] = a;
  }
  __syncthreads();
  if(tid < 16){
    float m = -1e30f;
    #pragma unroll
    for(int t=0;t<8;++t) m = fmaxf(m, wsm[tid][t]);
    float e[8], S=0.f;
    #pragma unroll
    for(int t=0;t<8;++t){ e[t] = __expf(wsm[tid][t]-m); S += e[t]; }
    const float inv = 1.f/S;
    #pragma unroll
    for(int t=0;t<8;++t) wsm[tid][t] = e[t]*inv;
  }
  __syncthreads();
  // z0 (reparameterized) on waves 0-3
  float zreg[4] = {0.f,0.f,0.f,0.f};
  if(w < 4){
    const int h=l>>4, st=l&15;
    s16x4 pk;
    #pragma unroll
    for(int r=0;r<4;++r){
      const int c = 16*w + 4*h + r;
      float mu0=0.f, lv0=0.f;
      #pragma unroll
      for(int t=0;t<8;++t){
        const float wv = wsm[st][t];
        mu0 = fmaf(wv, muB[(st*8+t)*64 + c], mu0);
        lv0 = fmaf(wv, lvB[(st*8+t)*64 + c], lv0);
      }
      const float z0 = fmaf(eps[(size_t)(b0+st)*64 + c], __expf(0.5f*lv0), mu0);
      zreg[r] = z0; pk[r] = f2b(z0);
      LATS[0][c][st] = z0;
    }
    *(s16x4*)(zB + (size_t)((2*w+(h>>1))*16+st)*8 + 4*(h&1)) = pk;
  }
  __syncthreads();

  for(int k=0;k<70;++k){
    float* latRow = (((k+1)%10)==0) ? &LATS[(k+1)/10][0][0] : nullptr;
    ivp_step(F, w, l, 0.1f*(float)k, 0.1f, zreg, zB, h1p, h2p, latRow);
  }

  // reconstruction MLP per t (f32; hR1/hR2 alias muB)
  float* hR1 = muB;            // [128][16]
  float* hR2 = muB + 128*16;   // [64][16]
  for(int t=0;t<TT;++t){
    {
      float acc[4]; const float b = rb1[c1];
      #pragma unroll
      for(int e=0;e<4;++e) acc[e]=b;
      for(int i=0;i<64;++i){
        const float wv = rW1[i*128 + c1];
        #pragma unroll
        for(int e=0;e<4;++e) acc[e] = fmaf(LATS[t][i][4*sh+e], wv, acc[e]);
      }
      #pragma unroll
      for(int e=0;e<4;++e) hR1[c1*16 + 4*sh + e] = lrelu(acc[e]);
    }
    __syncthreads();
    {
      float acc[2]; const float b = rb2[l];
      acc[0]=b; acc[1]=b;
      for(int i=0;i<128;++i){
        const float wv = rW2[i*64 + l];
        acc[0] = fmaf(hR1[i*16 + 2*w  ], wv, acc[0]);
        acc[1] = fmaf(hR1[i*16 + 2*w+1], wv, acc[1]);
      }
      hR2[l*16 + 2*w  ] = lrelu(acc[0]);
      hR2[l*16 + 2*w+1] = lrelu(acc[1]);
    }
    __syncthreads();
    if(tid < 32){
      const int s = tid >> 1, o = tid & 1;
      float a = rb3[o];
      for(int i=0;i<64;++i) a = fmaf(hR2[i*16 + s], rW3[i*2 + o], a);
      out[((size_t)(b0+s)*TT + t)*2 + o] = a;
    }
    __syncthreads();
  }
}

extern "C" void kernel_launch(void* const* d_in, const int* in_sizes, int n_in,
                              void* d_out, int out_size, void* d_ws, size_t ws_size,
                              hipStream_t stream){
  const float* features=(const float*)d_in[0];
  const float* eps     =(const float*)d_in[1];
  const float* feW1=(const float*)d_in[2];  const float* feb1=(const float*)d_in[3];
  const float* feW2=(const float*)d_in[4];  const float* feb2=(const float*)d_in[5];
  const float* feW3=(const float*)d_in[6];  const float* feb3=(const float*)d_in[7];
  const float* eA1=(const float*)d_in[8];   const float* ea1=(const float*)d_in[9];
  const float* eA2=(const float*)d_in[10];  const float* ea2=(const float*)d_in[11];
  const float* eA3=(const float*)d_in[12];  const float* ea3=(const float*)d_in[13];
  const float* pW1=(const float*)d_in[14];  const float* pb1=(const float*)d_in[15];
  const float* pW2=(const float*)d_in[16];  const float* pb2=(const float*)d_in[17];
  const float* mxW1=(const float*)d_in[18]; const float* mxb1=(const float*)d_in[19];
  const float* mxW2=(const float*)d_in[20]; const float* mxb2=(const float*)d_in[21];
  const float* dA1=(const float*)d_in[22];  const float* da1=(const float*)d_in[23];
  const float* dA2=(const float*)d_in[24];  const float* da2=(const float*)d_in[25];
  const float* dA3=(const float*)d_in[26];  const float* da3=(const float*)d_in[27];
  const float* rW1=(const float*)d_in[28];  const float* rb1=(const float*)d_in[29];
  const float* rW2=(const float*)d_in[30];  const float* rb2=(const float*)d_in[31];
  const float* rW3=(const float*)d_in[32];  const float* rb3=(const float*)d_in[33];

  float* ws_mu=(float*)d_ws;
  float* ws_lv=ws_mu + 512*8*64;

  k_enc<<<dim3(256),dim3(512),0,stream>>>(features,
      feW1,feb1,feW2,feb2,feW3,feb3,
      eA1,ea1,eA2,ea2,eA3,ea3,
      pW1,pb1,pW2,pb2,
      ws_mu, ws_lv);
  k_dec<<<dim3(32),dim3(512),0,stream>>>(ws_mu, ws_lv, eps,
      mxW1,mxb1,mxW2,mxb2,
      dA1,da1,dA2,da2,dA3,da3,
      rW1,rb1,rW2,rb2,rW3,rb3,
      (float*)d_out);
}